// Round 3
// baseline (303.082 us; speedup 1.0000x reference)
//
#include <hip/hip_runtime.h>

// PointPillarsScatter: out[b][c][y][x] = feat[m][c] where m is the LAST point
// (last-write-wins) with coordinates (b, _, y, x); 0 elsewhere.
// Strategy: winner-index pass (atomicMax on point index), then a
// block-cooperative gather:
//   phase 1: compact this block's occupied slots (LDS atomic ranks) and
//            bulk-stage their feat rows into LDS with dense float4 loads
//   phase 2: pure-store channel loop (4x4 register transpose, coalesced
//            1 KiB float4 stores), fragments read from LDS not HBM.
// Rationale: ~90% of slots are empty; per-lane guarded global loads put
// 262K mostly-idle VMEM load instrs + sparse 16B fetches into the store
// stream (gather ran at ~4.6 TB/s vs 6.2 TB/s pure-write fill).

#define NXc   512
#define NYc   512
#define Cc    64
#define CAP   160   // staged rows/block; mean occupancy ~98, cap = +6.6 sigma
#define ROWF  68    // floats per LDS row: 64 + 4 pad (bank de-phasing)

__global__ void __launch_bounds__(256)
winners_kernel(const int* __restrict__ coords, int* __restrict__ winner, int M) {
    int m = blockIdx.x * blockDim.x + threadIdx.x;
    if (m >= M) return;
    int4 cd = ((const int4*)coords)[m];          // [b, z, y, x] contiguous
    int slot = cd.x * (NYc * NXc) + cd.z * NXc + cd.w;
    atomicMax(&winner[slot], m);                 // last point (max m) wins
}

__global__ void __launch_bounds__(256)
gather_kernel(const float* __restrict__ feat, const int* __restrict__ winner,
              float* __restrict__ out) {
    __shared__ float rows[CAP * ROWF];           // 43.5 KiB -> 3 blocks/CU
    __shared__ int   widxs[CAP];
    __shared__ int   counter;

    const int tid  = threadIdx.x;
    const int gtid = blockIdx.x * 256 + tid;     // 0 .. B*NY*NX/4-1
    const int x4   = (gtid & (NXc / 4 - 1)) * 4; // 0..508 step 4
    const int by   = gtid >> 7;                  // NX/4 = 128 -> shift 7
    const int y    = by & (NYc - 1);
    const int b    = by >> 9;
    const int plane = NYc * NXc;                 // 262144

    if (tid == 0) counter = 0;
    __syncthreads();

    int4 w = *(const int4*)(winner + b * plane + y * NXc + x4);
    int cnt = (w.x >= 0) + (w.y >= 0) + (w.z >= 0) + (w.w >= 0);
    int base = 0;
    if (cnt) base = atomicAdd(&counter, cnt);    // LDS atomic: rank assignment

    int rr = base;
    int r0 = (w.x >= 0) ? rr++ : -1;
    int r1 = (w.y >= 0) ? rr++ : -1;
    int r2 = (w.z >= 0) ? rr++ : -1;
    int r3 = (w.w >= 0) ? rr++ : -1;
    if (r0 >= 0 && r0 < CAP) widxs[r0] = w.x;
    if (r1 >= 0 && r1 < CAP) widxs[r1] = w.y;
    if (r2 >= 0 && r2 < CAP) widxs[r2] = w.z;
    if (r3 >= 0 && r3 < CAP) widxs[r3] = w.w;
    __syncthreads();

    // Phase 1: dense cooperative stage of occupied rows (16B/lane, 16 lanes
    // per 256B row -> every load instruction moves 4 full row-segments).
    const int nOcc = min(counter, CAP);
    for (int i = tid; i < nOcc * 16; i += 256) {
        int row = i >> 4, seg = i & 15;
        float4 v = *(const float4*)(feat + (size_t)widxs[row] * Cc + seg * 4);
        *(float4*)(rows + row * ROWF + seg * 4) = v;
    }
    __syncthreads();

    // Phase 2: pure-store channel loop; fragments from LDS (or zero).
    // Global-load fallback only if a block ever exceeds CAP (correctness).
    float* obase = out + (size_t)(b * Cc) * plane + y * NXc + x4;

    #pragma unroll
    for (int cg = 0; cg < Cc / 4; ++cg) {
        float4 f0 = {0.f, 0.f, 0.f, 0.f};
        float4 f1 = f0, f2 = f0, f3 = f0;
        if (r0 >= 0) f0 = (r0 < CAP) ? *(const float4*)(rows + r0 * ROWF + cg * 4)
                                     : *(const float4*)(feat + (size_t)w.x * Cc + cg * 4);
        if (r1 >= 0) f1 = (r1 < CAP) ? *(const float4*)(rows + r1 * ROWF + cg * 4)
                                     : *(const float4*)(feat + (size_t)w.y * Cc + cg * 4);
        if (r2 >= 0) f2 = (r2 < CAP) ? *(const float4*)(rows + r2 * ROWF + cg * 4)
                                     : *(const float4*)(feat + (size_t)w.z * Cc + cg * 4);
        if (r3 >= 0) f3 = (r3 < CAP) ? *(const float4*)(rows + r3 * ROWF + cg * 4)
                                     : *(const float4*)(feat + (size_t)w.w * Cc + cg * 4);
        // transpose: channel c+i gets lane-slot-j value feat[m_j][c+i]
        float4 o;
        o = make_float4(f0.x, f1.x, f2.x, f3.x);
        *(float4*)(obase + (size_t)(cg * 4 + 0) * plane) = o;
        o = make_float4(f0.y, f1.y, f2.y, f3.y);
        *(float4*)(obase + (size_t)(cg * 4 + 1) * plane) = o;
        o = make_float4(f0.z, f1.z, f2.z, f3.z);
        *(float4*)(obase + (size_t)(cg * 4 + 2) * plane) = o;
        o = make_float4(f0.w, f1.w, f2.w, f3.w);
        *(float4*)(obase + (size_t)(cg * 4 + 3) * plane) = o;
    }
}

extern "C" void kernel_launch(void* const* d_in, const int* in_sizes, int n_in,
                              void* d_out, int out_size, void* d_ws, size_t ws_size,
                              hipStream_t stream) {
    const float* feat   = (const float*)d_in[0];
    const int*   coords = (const int*)d_in[1];
    float*       out    = (float*)d_out;

    const int M = in_sizes[1] / 4;                 // coordinates is (M,4)
    const int B = out_size / (Cc * NYc * NXc);     // 4

    int* winner = (int*)d_ws;                      // B*NY*NX ints = 4 MiB
    const size_t wbytes = (size_t)B * NYc * NXc * sizeof(int);

    // winner = -1 everywhere (0xFFFFFFFF). ws is re-poisoned each call, so
    // this must run every launch. Memset nodes are graph-capturable.
    hipMemsetAsync(winner, 0xFF, wbytes, stream);

    winners_kernel<<<(M + 255) / 256, 256, 0, stream>>>(coords, winner, M);

    const int nthreads = B * NYc * NXc / 4;        // 262144
    gather_kernel<<<nthreads / 256, 256, 0, stream>>>(feat, winner, out);
}